// Round 7
// baseline (203.969 us; speedup 1.0000x reference)
//
#include <hip/hip_runtime.h>
#include <math.h>

// Problem constants
#define BQ 64
#define NOBJ 5
#define CIN 3
#define IMG_H 64
#define IMG_W 96
#define OH 32
#define OW 48
#define OC 128
#define NPAIR 25
#define PP 4
#define CONV_OUT 32

// Tiling: each conv block = (src, b, rowgroup of 2 output rows)
#define NRG 16                          // 32 output rows / 2
#define NPOS 96                         // 2 output rows x 48 cols
#define XK 32                           // padded K (27 real + bias + zeros)
#define X_ELEMS (NOBJ * NPOS * XK)      // 15360 shorts = 30.7 KB per (src,b,rg)
#define X_UNITS (NOBJ * NPOS * 4)       // 1920 short8 units per tile

#define NPRED (2 * 1600 * PP)           // 12800
#define ADJ_N (BQ * 1600)               // 102400

#define X_BYTES   ((size_t)2 * BQ * NRG * X_ELEMS * 2)   // 62,914,560
#define T_OFFSET  0
#define X_OFFSET  2097152               // X starts 2 MB into ws
#define WS_NEEDED (X_OFFSET + X_BYTES)

typedef __attribute__((ext_vector_type(8))) short short8;
typedef __attribute__((ext_vector_type(4))) float float4_;
typedef __attribute__((ext_vector_type(2))) float pf2;

__device__ inline unsigned short f2bf(float f) {
    unsigned u = __builtin_bit_cast(unsigned, f);
    u += 0x7fff + ((u >> 16) & 1);          // round-to-nearest-even
    return (unsigned short)(u >> 16);
}

// ---------------- shared compute core (post-staging) ----------------
// Assumes sX[obj][pos][k] fragments staged in LDS; this wave owns oc-tile mt=wave.
__device__ __forceinline__ void compute_and_store(
    const unsigned short* sX,
    const float* __restrict__ conv_w,
    const float* __restrict__ conv_b,
    const float* __restrict__ w2,
    float* __restrict__ T,
    int src, int b, int rg, int tid)
{
    const int wave = tid >> 6;      // 0..7 -> mt
    const int lane = tid & 63;
    const int quad = lane >> 4;
    const int ocl  = lane & 15;

    const int mt  = wave;
    const int p   = mt >> 1;
    const int row = mt * 16 + ocl;  // this lane's weight row (oc)

    // weights straight from global (27 KB, L2-resident), bias at k=27
    short8 wa, wb;
    #pragma unroll
    for (int j = 0; j < 8; ++j) {
        int k = quad * 8 + j;
        float va = 0.f, vb = 0.f;
        if (k < 27) {
            va = conv_w[row * 54 + k];
            vb = conv_w[row * 54 + 27 + k];
        } else if (k == 27) {
            va = conv_b[row];
        }
        wa[j] = (short)f2bf(va);
        wb[j] = (short)f2bf(vb);
    }
    pf2 w2lo, w2hi;
    w2lo[0] = w2[p * CONV_OUT + (mt & 1) * 16 + quad * 4 + 0];
    w2lo[1] = w2[p * CONV_OUT + (mt & 1) * 16 + quad * 4 + 1];
    w2hi[0] = w2[p * CONV_OUT + (mt & 1) * 16 + quad * 4 + 2];
    w2hi[1] = w2[p * CONV_OUT + (mt & 1) * 16 + quad * 4 + 3];

    __syncthreads();

    const float4_ zero4 = {0.f, 0.f, 0.f, 0.f};

    pf2 acc2[NPAIR];
    #pragma unroll
    for (int q = 0; q < NPAIR; ++q) { acc2[q][0] = 0.f; acc2[q][1] = 0.f; }

    #pragma unroll
    for (int nt = 0; nt < 6; ++nt) {    // 2 rows x 3 col-tiles of 16 (FULL unroll)
        const int rl  = nt / 3;
        const int c0  = (nt - rl * 3) * 16;
        const int pos = rl * 48 + c0 + ocl;

        pf2 alo[NOBJ], ahi[NOBJ];
        short8 xf[NOBJ];
        #pragma unroll
        for (int obj = 0; obj < NOBJ; ++obj) {
            xf[obj] = *(const short8*)&sX[((size_t)(obj * NPOS + pos)) * XK + quad * 8];
            float4_ a = __builtin_amdgcn_mfma_f32_16x16x32_bf16(wa, xf[obj], zero4, 0, 0, 0);
            alo[obj][0] = a[0]; alo[obj][1] = a[1];
            ahi[obj][0] = a[2]; ahi[obj][1] = a[3];
        }

        #pragma unroll
        for (int jo = 0; jo < NOBJ; ++jo) {
            float4_ bq = __builtin_amdgcn_mfma_f32_16x16x32_bf16(wb, xf[jo], zero4, 0, 0, 0);
            pf2 blo, bhi;
            blo[0] = bq[0]; blo[1] = bq[1];
            bhi[0] = bq[2]; bhi[1] = bq[3];
            #pragma unroll
            for (int i = 0; i < NOBJ; ++i) {
                pf2 v0 = alo[i] + blo;              // v_pk_add_f32
                pf2 v1 = ahi[i] + bhi;
                v0[0] = fmaxf(v0[0], 0.f); v0[1] = fmaxf(v0[1], 0.f);
                v1[0] = fmaxf(v1[0], 0.f); v1[1] = fmaxf(v1[1], 0.f);
                acc2[i * NOBJ + jo] += v0 * w2lo + v1 * w2hi;   // pk_fma x2
            }
        }
    }

    // ---- wave-reduce each pair across 64 lanes; direct store (no atomics) ----
    float myv = 0.f;
    #pragma unroll
    for (int q = 0; q < NPAIR; ++q) {
        float rr = acc2[q][0] + acc2[q][1];
        #pragma unroll
        for (int off = 32; off > 0; off >>= 1)
            rr += __shfl_xor(rr, off, 64);
        if (lane == q) myv = rr;
    }
    if (lane < NPAIR)
        T[((((size_t)src * BQ + b) * NRG + rg) * NPAIR + lane) * 8 + mt] = myv;
}

// ---------------- split path: kernel A builds X (+adj), kernel B computes ----
__global__ __launch_bounds__(256) void im2col_kernel(
    const float* __restrict__ state,
    const float* __restrict__ state_next,
    unsigned short* __restrict__ X,
    float* __restrict__ out)
{
    const int tid = threadIdx.x;
    const int rg  = blockIdx.x;     // 0..15
    const int b   = blockIdx.y;     // 0..63
    const int src = blockIdx.z;     // 0..1

    // adj mask from src==1 blocks
    if (src == 1 && tid < 100) {
        int a  = (rg + NRG * b) * 100 + tid;
        int bb = a / 1600;
        int t  = a - bb * 1600;
        out[NPRED + a] = (t / NPAIR == bb) ? 1.0f : 0.0f;
    }

    const float* g = (src == 0 ? state : state_next)
                   + (size_t)b * NOBJ * CIN * IMG_H * IMG_W;
    const int R0 = rg * 4;
    unsigned short* xb = X + ((size_t)((src * BQ + b) * NRG + rg)) * X_ELEMS;

    const int subk = tid & 3;       // preserved by += 256 stepping
    int koff[8], khv[8], kwv[8];
    unsigned short padv[8];
    bool kval[8];
    #pragma unroll
    for (int j = 0; j < 8; ++j) {
        int k = subk * 8 + j;
        if (k < 27) {
            int ci = k / 9;
            int r9 = k - ci * 9;
            int kh = r9 / 3;
            int kw = r9 - kh * 3;
            koff[j] = ci * (IMG_H * IMG_W) + kh * IMG_W + kw;
            khv[j] = kh; kwv[j] = kw; kval[j] = true; padv[j] = 0;
        } else {
            koff[j] = 0; khv[j] = 0; kwv[j] = 0; kval[j] = false;
            padv[j] = (k == 27) ? (unsigned short)0x3f80 : (unsigned short)0;
        }
    }

    #pragma unroll
    for (int t = 0; t < 8; ++t) {
        int u = tid + 256 * t;
        if (u < X_UNITS) {
            int pl  = (u >> 2) % NPOS;
            int obj = u / (NPOS * 4);
            int rl  = (pl >= 48) ? 1 : 0;
            int pc  = pl - rl * 48;
            int gr0 = R0 + 2 * rl;
            int gc0 = 2 * pc;
            const float* gp = g + obj * (CIN * IMG_H * IMG_W) + gr0 * IMG_W + gc0;
            short8 vals;
            #pragma unroll
            for (int j = 0; j < 8; ++j) {
                unsigned short hv = padv[j];
                if (kval[j] && (gr0 + khv[j] < IMG_H) && (gc0 + kwv[j] < IMG_W))
                    hv = f2bf(gp[koff[j]]);
                vals[j] = (short)hv;
            }
            *(short8*)&xb[(size_t)u * 8] = vals;    // coalesced 16B stores
        }
    }
}

__global__ __launch_bounds__(512) void conv_pair_mfma_split(
    const unsigned short* __restrict__ X,
    const float* __restrict__ conv_w,
    const float* __restrict__ conv_b,
    const float* __restrict__ w2,
    float* __restrict__ T)
{
    __shared__ __align__(16) unsigned short sX[X_ELEMS];   // 30.7 KB

    const int tid = threadIdx.x;
    const int rg  = blockIdx.x;
    const int b   = blockIdx.y;
    const int src = blockIdx.z;

    const unsigned short* xb = X + ((size_t)((src * BQ + b) * NRG + rg)) * X_ELEMS;
    const int wave = tid >> 6;
    const int lane = tid & 63;

    // stage: 30 x 1KB coalesced copies (wave-uniform chunks, conflict-free writes)
    #pragma unroll
    for (int t = 0; t < 4; ++t) {
        int i = wave + 8 * t;
        if (i < 30) {
            short8 v = *(const short8*)&xb[(size_t)i * 512 + lane * 8];
            *(short8*)&sX[(size_t)i * 512 + lane * 8] = v;
        }
    }

    compute_and_store(sX, conv_w, conv_b, w2, T, src, b, rg, tid);
}

// ---------------- fused fallback (R6 structure) if ws too small ----------------
__global__ __launch_bounds__(512) void conv_pair_mfma_fused(
    const float* __restrict__ state,
    const float* __restrict__ state_next,
    const float* __restrict__ conv_w,
    const float* __restrict__ conv_b,
    const float* __restrict__ w2,
    float* __restrict__ T,
    float* __restrict__ out)
{
    __shared__ __align__(16) unsigned short sX[X_ELEMS];

    const int tid = threadIdx.x;
    const int rg  = blockIdx.x;
    const int b   = blockIdx.y;
    const int src = blockIdx.z;

    const float* g = (src == 0 ? state : state_next)
                   + (size_t)b * NOBJ * CIN * IMG_H * IMG_W;
    const int R0 = rg * 4;

    if (src == 1 && tid < 100) {
        int a  = (rg + NRG * b) * 100 + tid;
        int bb = a / 1600;
        int t  = a - bb * 1600;
        out[NPRED + a] = (t / NPAIR == bb) ? 1.0f : 0.0f;
    }

    {
        const int subk = tid & 3;
        int koff[8], khv[8], kwv[8];
        unsigned short padv[8];
        bool kval[8];
        #pragma unroll
        for (int j = 0; j < 8; ++j) {
            int k = subk * 8 + j;
            if (k < 27) {
                int ci = k / 9;
                int r9 = k - ci * 9;
                int kh = r9 / 3;
                int kw = r9 - kh * 3;
                koff[j] = ci * (IMG_H * IMG_W) + kh * IMG_W + kw;
                khv[j] = kh; kwv[j] = kw; kval[j] = true; padv[j] = 0;
            } else {
                koff[j] = 0; khv[j] = 0; kwv[j] = 0; kval[j] = false;
                padv[j] = (k == 27) ? (unsigned short)0x3f80 : (unsigned short)0;
            }
        }
        for (int u = tid; u < X_UNITS; u += 512) {
            int pl  = (u >> 2) % NPOS;
            int obj = u / (NPOS * 4);
            int rl  = (pl >= 48) ? 1 : 0;
            int pc  = pl - rl * 48;
            int gr0 = R0 + 2 * rl;
            int gc0 = 2 * pc;
            const float* gp = g + obj * (CIN * IMG_H * IMG_W) + gr0 * IMG_W + gc0;
            short8 vals;
            #pragma unroll
            for (int j = 0; j < 8; ++j) {
                unsigned short hv = padv[j];
                if (kval[j] && (gr0 + khv[j] < IMG_H) && (gc0 + kwv[j] < IMG_W))
                    hv = f2bf(gp[koff[j]]);
                vals[j] = (short)hv;
            }
            *(short8*)&sX[(size_t)u * 8] = vals;
        }
    }

    compute_and_store(sX, conv_w, conv_b, w2, T, src, b, rg, tid);
}

// predicates only: 12800 threads
__global__ __launch_bounds__(256) void pred_kernel(
    const float* __restrict__ T,
    const float* __restrict__ b2,
    const float* __restrict__ temp,
    float* __restrict__ out)
{
    int idx = blockIdx.x * blockDim.x + threadIdx.x;
    if (idx >= NPRED) return;
    int p   = idx & 3;
    int t   = (idx >> 2) % 1600;
    int src = idx / 6400;
    int bb  = t / NPAIR;
    int pr  = t - bb * NPAIR;
    const float* base = T + ((((size_t)src * BQ + bb) * NRG) * NPAIR + pr) * 8 + 2 * p;
    float sum = 0.f;
    #pragma unroll
    for (int rgi = 0; rgi < NRG; ++rgi) {
        sum += base[(size_t)rgi * NPAIR * 8];
        sum += base[(size_t)rgi * NPAIR * 8 + 1];
    }
    float logit = sum * (1.0f / (OH * OW)) + b2[p];
    float x = logit / temp[0];
    out[idx] = 1.0f / (1.0f + expf(-x));
}

extern "C" void kernel_launch(void* const* d_in, const int* in_sizes, int n_in,
                              void* d_out, int out_size, void* d_ws, size_t ws_size,
                              hipStream_t stream)
{
    const float* state      = (const float*)d_in[0];
    const float* state_next = (const float*)d_in[1];
    const float* conv_w     = (const float*)d_in[2];
    const float* conv_b     = (const float*)d_in[3];
    const float* w2         = (const float*)d_in[4];
    const float* b2         = (const float*)d_in[5];
    // d_in[6] = n_obj (always 5)
    const float* temp       = (const float*)d_in[7];

    float* out = (float*)d_out;
    float* T   = (float*)((char*)d_ws + T_OFFSET);   // 1.64 MB

    dim3 grid1(NRG, BQ, 2);

    if (ws_size >= WS_NEEDED) {
        unsigned short* X = (unsigned short*)((char*)d_ws + X_OFFSET);
        im2col_kernel<<<grid1, 256, 0, stream>>>(state, state_next, X, out);
        conv_pair_mfma_split<<<grid1, 512, 0, stream>>>(X, conv_w, conv_b, w2, T);
    } else {
        conv_pair_mfma_fused<<<grid1, 512, 0, stream>>>(state, state_next, conv_w,
                                                        conv_b, w2, T, out);
    }

    pred_kernel<<<(NPRED + 255) / 256, 256, 0, stream>>>(T, b2, temp, out);
}

// Round 9
// 152.878 us; speedup vs baseline: 1.3342x; 1.3342x over previous
//
#include <hip/hip_runtime.h>
#include <math.h>

// Problem constants
#define BQ 64
#define NOBJ 5
#define CIN 3
#define IMG_H 64
#define IMG_W 96
#define OH 32
#define OW 48
#define NPAIR 25
#define PP 4
#define CONV_OUT 32

// Tiling: each block = (src, b, rowgroup of 2 output rows); 512 threads = 8 waves
#define NRG 16                          // 32 output rows / 2
#define NPOS 96                         // 2 output rows x 48 cols
#define XK 32                           // padded K (27 real + bias + zeros)
#define X_U32 (NOBJ * NPOS * XK / 2)    // 7680 u32 = 30.7 KB (f16 im2col)
#define X_UNITS (NOBJ * NPOS * 4)       // 1920 8-elem units

#define NPRED (2 * 1600 * PP)           // 12800
#define ADJ_N (BQ * 1600)               // 102400

typedef __fp16   h2 __attribute__((ext_vector_type(2)));     // cvt_pkrtz result type
typedef _Float16 half8 __attribute__((ext_vector_type(8)));  // MFMA A/B operand
typedef float    float4_ __attribute__((ext_vector_type(4)));
typedef unsigned int uint4_ __attribute__((ext_vector_type(4)));

// T[src][b][rg][pair][mt]; mt = 16-oc tile 0..7 (p = mt>>1). Fully written,
// no memset, no atomics. src==1 blocks also write the adj mask.
__global__ __launch_bounds__(512) void conv_pair_mfma(
    const float* __restrict__ state,
    const float* __restrict__ state_next,
    const float* __restrict__ conv_w,
    const float* __restrict__ conv_b,
    const float* __restrict__ w2,
    float* __restrict__ T,
    float* __restrict__ out)
{
    __shared__ __align__(16) unsigned int sX32[X_U32];   // 30.7 KB f16 im2col

    const int tid = threadIdx.x;
    const int rg  = blockIdx.x;     // 0..15
    const int b   = blockIdx.y;     // 0..63
    const int src = blockIdx.z;     // 0..1

    const float* g = (src == 0 ? state : state_next)
                   + (size_t)b * NOBJ * CIN * IMG_H * IMG_W;
    const int R0 = rg * 4;          // first input row of this rowgroup

    // ---- adj mask from src==1 blocks (independent; pre-barrier) ----
    if (src == 1 && tid < 100) {
        int a  = (rg + NRG * b) * 100 + tid;     // 1024 blocks x 100 = 102400
        int bb = a / 1600;
        int t  = a - bb * 1600;
        out[NPRED + a] = (t / NPAIR == bb) ? 1.0f : 0.0f;
    }

    const int wave = tid >> 6;      // 0..7 -> mt
    const int lane = tid & 63;
    const int quad = lane >> 4;
    const int ocl  = lane & 15;

    const int mt  = wave;
    const int p   = mt >> 1;
    const int row = mt * 16 + ocl;  // this lane's conv_w row (oc)

    // ---- per-lane weights as f16 (global loads issue early, overlap staging)
    half8 wa, wb;
    #pragma unroll
    for (int j = 0; j < 8; ++j) {
        int k = quad * 8 + j;
        float va = 0.f, vb = 0.f;
        if (k < 27) {
            va = conv_w[row * 54 + k];
            vb = conv_w[row * 54 + 27 + k];
        } else if (k == 27) {
            va = conv_b[row];       // bias pairs with 1.0 lane in X
        }
        wa[j] = (_Float16)va;
        wb[j] = (_Float16)vb;
    }
    h2 w2h01, w2h23;
    {
        const float* wp = w2 + p * CONV_OUT + (mt & 1) * 16 + quad * 4;
        w2h01 = __builtin_amdgcn_cvt_pkrtz(wp[0], wp[1]);
        w2h23 = __builtin_amdgcn_cvt_pkrtz(wp[2], wp[3]);
    }

    // ---- build f16 im2col sX[obj][pos][k] directly from global.
    // unit u = obj*384 + pos*4 + subk; subk = tid&3 invariant under += 512.
    // k = subk*8+j; k==27 -> 1.0 (bias partner), k>27 -> 0, OOB -> 0.
    {
        const int subk = tid & 3;
        int koff[8], khv[8], kwv[8];
        float padf[8];
        bool kval[8];
        #pragma unroll
        for (int j = 0; j < 8; ++j) {
            int k = subk * 8 + j;
            if (k < 27) {
                int ci = k / 9;
                int r9 = k - ci * 9;
                int kh = r9 / 3;
                int kw = r9 - kh * 3;
                koff[j] = ci * (IMG_H * IMG_W) + kh * IMG_W + kw;
                khv[j] = kh; kwv[j] = kw; kval[j] = true; padf[j] = 0.f;
            } else {
                koff[j] = 0; khv[j] = 0; kwv[j] = 0; kval[j] = false;
                padf[j] = (k == 27) ? 1.0f : 0.f;
            }
        }
        for (int u = tid; u < X_UNITS; u += 512) {
            int pl  = (u >> 2) % NPOS;
            int obj = u / (NPOS * 4);
            int rl  = (pl >= 48) ? 1 : 0;
            int pc  = pl - rl * 48;
            int gr0 = R0 + 2 * rl;
            int gc0 = 2 * pc;
            const float* gp = g + obj * (CIN * IMG_H * IMG_W) + gr0 * IMG_W + gc0;
            float fv[8];
            #pragma unroll
            for (int j = 0; j < 8; ++j) {
                float v = padf[j];
                if (kval[j] && (gr0 + khv[j] < IMG_H) && (gc0 + kwv[j] < IMG_W))
                    v = gp[koff[j]];
                fv[j] = v;
            }
            uint4_ w4;
            w4.x = __builtin_bit_cast(unsigned int, __builtin_amdgcn_cvt_pkrtz(fv[0], fv[1]));
            w4.y = __builtin_bit_cast(unsigned int, __builtin_amdgcn_cvt_pkrtz(fv[2], fv[3]));
            w4.z = __builtin_bit_cast(unsigned int, __builtin_amdgcn_cvt_pkrtz(fv[4], fv[5]));
            w4.w = __builtin_bit_cast(unsigned int, __builtin_amdgcn_cvt_pkrtz(fv[6], fv[7]));
            *(uint4_*)&sX32[(size_t)u * 4] = w4;    // contiguous 16B writes
        }
    }

    __syncthreads();

    const float4_ zero4 = {0.f, 0.f, 0.f, 0.f};
    const h2 hz = {(__fp16)0.f, (__fp16)0.f};

    float acc[NPAIR];
    #pragma unroll
    for (int q = 0; q < NPAIR; ++q) acc[q] = 0.f;

    #pragma unroll
    for (int nt = 0; nt < 6; ++nt) {    // 2 rows x 3 col-tiles of 16
        const int rl  = nt / 3;
        const int c0  = (nt - rl * 3) * 16;
        const int pos = rl * 48 + c0 + ocl;

        half8 xf[NOBJ];
        h2 ah01[NOBJ], ah23[NOBJ];
        #pragma unroll
        for (int obj = 0; obj < NOBJ; ++obj) {
            xf[obj] = *(const half8*)&sX32[((size_t)(obj * NPOS + pos)) * 16 + quad * 4];
            float4_ a = __builtin_amdgcn_mfma_f32_16x16x32_f16(wa, xf[obj], zero4, 0, 0, 0);
            ah01[obj] = __builtin_amdgcn_cvt_pkrtz(a[0], a[1]);
            ah23[obj] = __builtin_amdgcn_cvt_pkrtz(a[2], a[3]);
        }

        #pragma unroll
        for (int jo = 0; jo < NOBJ; ++jo) {
            float4_ bq = __builtin_amdgcn_mfma_f32_16x16x32_f16(wb, xf[jo], zero4, 0, 0, 0);
            h2 bh01 = __builtin_amdgcn_cvt_pkrtz(bq[0], bq[1]);
            h2 bh23 = __builtin_amdgcn_cvt_pkrtz(bq[2], bq[3]);
            #pragma unroll
            for (int i = 0; i < NOBJ; ++i) {
                h2 s0 = ah01[i] + bh01;                        // v_pk_add_f16
                h2 s1 = ah23[i] + bh23;
                s0 = __builtin_elementwise_max(s0, hz);        // v_pk_max_f16
                s1 = __builtin_elementwise_max(s1, hz);
                float t0 = __builtin_amdgcn_fdot2(s0, w2h01, acc[i * NOBJ + jo], false);
                acc[i * NOBJ + jo] = __builtin_amdgcn_fdot2(s1, w2h23, t0, false);
            }
        }
    }

    // ---- wave-reduce each pair across 64 lanes; direct store (no atomics) ----
    float myv = 0.f;
    #pragma unroll
    for (int q = 0; q < NPAIR; ++q) {
        float rr = acc[q];
        #pragma unroll
        for (int off = 32; off > 0; off >>= 1)
            rr += __shfl_xor(rr, off, 64);
        if (lane == q) myv = rr;
    }
    if (lane < NPAIR)
        T[((((size_t)src * BQ + b) * NRG + rg) * NPAIR + lane) * 8 + mt] = myv;
}

// predicates only: 12800 threads
__global__ __launch_bounds__(256) void pred_kernel(
    const float* __restrict__ T,
    const float* __restrict__ b2,
    const float* __restrict__ temp,
    float* __restrict__ out)
{
    int idx = blockIdx.x * blockDim.x + threadIdx.x;
    if (idx >= NPRED) return;
    int p   = idx & 3;
    int t   = (idx >> 2) % 1600;
    int src = idx / 6400;
    int bb  = t / NPAIR;
    int pr  = t - bb * NPAIR;
    const float* base = T + ((((size_t)src * BQ + bb) * NRG) * NPAIR + pr) * 8 + 2 * p;
    float sum = 0.f;
    #pragma unroll
    for (int rgi = 0; rgi < NRG; ++rgi) {
        sum += base[(size_t)rgi * NPAIR * 8];
        sum += base[(size_t)rgi * NPAIR * 8 + 1];
    }
    float logit = sum * (1.0f / (OH * OW)) + b2[p];
    float x = logit / temp[0];
    out[idx] = 1.0f / (1.0f + expf(-x));
}

extern "C" void kernel_launch(void* const* d_in, const int* in_sizes, int n_in,
                              void* d_out, int out_size, void* d_ws, size_t ws_size,
                              hipStream_t stream)
{
    const float* state      = (const float*)d_in[0];
    const float* state_next = (const float*)d_in[1];
    const float* conv_w     = (const float*)d_in[2];
    const float* conv_b     = (const float*)d_in[3];
    const float* w2         = (const float*)d_in[4];
    const float* b2         = (const float*)d_in[5];
    // d_in[6] = n_obj (always 5)
    const float* temp       = (const float*)d_in[7];

    float* out = (float*)d_out;
    float* T   = (float*)d_ws;              // [2][64][16][25][8] floats = 1.64 MB

    dim3 grid1(NRG, BQ, 2);                 // 2048 blocks x 512 threads
    conv_pair_mfma<<<grid1, 512, 0, stream>>>(state, state_next, conv_w, conv_b,
                                              w2, T, out);

    pred_kernel<<<(NPRED + 255) / 256, 256, 0, stream>>>(T, b2, temp, out);
}